// Round 2
// baseline (3740.064 us; speedup 1.0000x reference)
//
#include <hip/hip_runtime.h>
#include <math.h>

#define BB 32
#define CC 3
#define HH 224
#define WW 224
#define HWS (HH*WW)            // 50176
#define NPIX (BB*HWS)          // 1,605,632
#define NTAPS (9*HWS)          // 451,584
#define EPS_IN 1e-5f
#define LNUM 10

// 2D tile: 8 rows x 32 cols per block, halo RAD=7 on each side
#define TR 8
#define TC 32
#define RAD 7
#define WROWS (TR + 2*RAD)         // 22
#define WCOLS (TC + 2*RAD)         // 46
#define WCELLS (WROWS * WCOLS)     // 1012
#define NTILE ((HH/TR) * (WW/TC))  // 28*7 = 196
#define NBLK (NTILE * BB)          // 6272

__device__ __forceinline__ float fast_tanh(float z) {
    z = fminf(fmaxf(z, -15.f), 15.f);
    float e = __expf(2.f * z);
    return (e - 1.f) * __frcp_rn(e + 1.f);
}

// ---------------- zero stats ----------------
__global__ void zero_kernel(float* __restrict__ p, int n) {
    int i = blockIdx.x * 256 + threadIdx.x;
    if (i < n) p[i] = 0.f;
}

// ------- compact taps: absolute fractional sample coords (py,px), 8B/tap ------
__global__ __launch_bounds__(256) void taps_kernel(
    const float* __restrict__ off,   // [18,H,W] batch-0 offset plane
    float2* __restrict__ tp)         // [9,HW]
{
    int gid = blockIdx.x * 256 + threadIdx.x;    // k*HWS + pix, grid exact
    int k = gid / HWS, pix = gid - k * HWS;
    int h = pix / WW, wc = pix - h * WW;
    int ky = k / 3, kx = k - 3 * ky;
    float dy = off[(2 * k)     * HWS + pix];
    float dx = off[(2 * k + 1) * HWS + pix];
    float py = (float)(h  + ky - 1) + dy;
    float px = (float)(wc + kx - 1) + dx;
    tp[gid] = make_float2(py, px);
}

// ------- pack planar x [B,3,H,W] -> interleaved [B,H,W,4] (once) -------
__global__ __launch_bounds__(256) void pack_kernel(
    const float* __restrict__ x, float4* __restrict__ xi)
{
    int g = blockIdx.x * 256 + threadIdx.x;      // grid exact: NPIX
    int b = g / HWS, pix = g - b * HWS;
    const float* xb = x + (size_t)b * (CC * HWS) + pix;
    xi[g] = make_float4(xb[0], xb[HWS], xb[2 * HWS], 0.f);
}

// ---------------- fused deformable conv + (prev-layer norm/tanh) ----------------
// R1 post-mortem: conv is bound by TCP cacheline transactions (~1 line/cyc/CU):
// gathers re-touch the same lines ~9x (L1 thrashes at 4 x 18KB windows/CU).
// Fix: stage the 22x46 float4 window in LDS once (63 B/pixel TCP vs 576),
// read corners via contiguous ds_read_b128 (conflict-free, 85 B/cyc).
// Taps compacted to float2 (py,px): 72 B/pixel streamed, expanded in VALU.
// Norm+tanh of the PREVIOUS layer is applied during staging (stats from the
// previous kernel are complete at the kernel boundary) -> 10 norm dispatches
// and a 51 MB/iter pass are eliminated. Rare taps whose corners fall outside
// the halo (|offset| > ~6) take an exec-masked global fallback, so
// correctness never depends on RAD.
template<int DO_NORM>
__global__ __launch_bounds__(256, 4) void conv_fused(
    const float4* __restrict__ xi,       // prev RAW activations [B*HWS] interleaved
    const float2* __restrict__ tp,       // [9,HW] absolute (py,px)
    const float*  __restrict__ wt,       // [3,3,9]
    const float*  __restrict__ stats_in, // [B*3][2] of prev layer (DO_NORM=1)
    const float*  __restrict__ gamma,
    const float*  __restrict__ beta,
    float4* __restrict__ yo,             // RAW conv out [B*HWS]
    float* __restrict__ stats_out)       // [B*3][2] of this layer
{
    __shared__ float4 win[WCELLS];
    __shared__ float  w_s[81];
    __shared__ float  red[4][6];

    int t = threadIdx.x;
    if (t < 81) w_s[t] = wt[t];

    int p = blockIdx.x;
    int logical = (p & 7) * (NBLK / 8) + (p >> 3);
    int b    = logical & 31;             // batches adjacent -> tap L2 reuse
    int tile = logical >> 5;             // 0..195
    int ty = tile / 7, tx = tile - ty * 7;
    int by0 = ty * TR, bx0 = tx * TC;
    int wly = by0 - RAD, wlx = bx0 - RAD;

    // uniform per-(b,c) norm params of the PREVIOUS layer
    float mean0=0.f, mean1=0.f, mean2=0.f;
    float g0=1.f, g1=1.f, g2=1.f, bt0=0.f, bt1=0.f, bt2=0.f;
    if (DO_NORM) {
        const float* st = stats_in + b * 6;
        mean0 = st[0] * (1.f/HWS); mean1 = st[2] * (1.f/HWS); mean2 = st[4] * (1.f/HWS);
        float v0 = fmaxf(st[1]*(1.f/HWS) - mean0*mean0, 0.f);
        float v1 = fmaxf(st[3]*(1.f/HWS) - mean1*mean1, 0.f);
        float v2 = fmaxf(st[5]*(1.f/HWS) - mean2*mean2, 0.f);
        g0 = gamma[0] * rsqrtf(v0 + EPS_IN); bt0 = beta[0];
        g1 = gamma[1] * rsqrtf(v1 + EPS_IN); bt1 = beta[1];
        g2 = gamma[2] * rsqrtf(v2 + EPS_IN); bt2 = beta[2];
    }

    const float4* xb = xi + (size_t)b * HWS;

    int ry = t >> 5, rx = t & 31;
    int pix = (by0 + ry) * WW + (bx0 + rx);

    // issue tap loads early (independent stream, overlaps staging)
    float2 tpk[9];
    #pragma unroll
    for (int k = 0; k < 9; ++k) tpk[k] = tp[k * HWS + pix];

    // ---- stage window (norm+tanh of prev layer applied on the fly) ----
    #pragma unroll
    for (int i = 0; i < 4; ++i) {
        int cell = t + i * 256;
        if (cell < WCELLS) {
            int wy = cell / WCOLS, wx = cell - wy * WCOLS;
            int gy = min(max(wly + wy, 0), HH - 1);   // clamp: value only used
            int gx = min(max(wlx + wx, 0), WW - 1);   // when weight-masked != 0
            float4 v = xb[gy * WW + gx];
            if (DO_NORM) {
                v.x = fast_tanh((v.x - mean0) * g0 + bt0);
                v.y = fast_tanh((v.y - mean1) * g1 + bt1);
                v.z = fast_tanh((v.z - mean2) * g2 + bt2);
            }
            win[cell] = v;
        }
    }
    __syncthreads();

    float acc0 = 0.f, acc1 = 0.f, acc2 = 0.f;

    #pragma unroll
    for (int k = 0; k < 9; ++k) {
        float py = tpk[k].x, px = tpk[k].y;
        float y0f = floorf(py), x0f = floorf(px);
        float fy = py - y0f, fx = px - x0f;
        int iy0 = (int)y0f, ix0 = (int)x0f;
        int iy1 = iy0 + 1,  ix1 = ix0 + 1;
        float vy0 = (iy0 >= 0 && iy0 < HH) ? 1.f : 0.f;
        float vy1 = (iy1 >= 0 && iy1 < HH) ? 1.f : 0.f;
        float vx0 = (ix0 >= 0 && ix0 < WW) ? 1.f : 0.f;
        float vx1 = (ix1 >= 0 && ix1 < WW) ? 1.f : 0.f;
        float w00 = (1.f - fy) * (1.f - fx) * vy0 * vx0;
        float w01 = (1.f - fy) * fx         * vy0 * vx1;
        float w10 = fy         * (1.f - fx) * vy1 * vx0;
        float w11 = fy         * fx         * vy1 * vx1;

        float4 v00, v01, v10, v11;
        if (iy0 >= wly && iy0 <= wly + WROWS - 2 &&
            ix0 >= wlx && ix0 <= wlx + WCOLS - 2) {
            int base = (iy0 - wly) * WCOLS + (ix0 - wlx);
            v00 = win[base];         v01 = win[base + 1];
            v10 = win[base + WCOLS]; v11 = win[base + WCOLS + 1];
        } else {
            // rare big-offset fallback: clamped global read + inline norm
            int cy0 = min(max(iy0, 0), HH - 1), cy1 = min(max(iy1, 0), HH - 1);
            int cx0 = min(max(ix0, 0), WW - 1), cx1 = min(max(ix1, 0), WW - 1);
            v00 = xb[cy0 * WW + cx0]; v01 = xb[cy0 * WW + cx1];
            v10 = xb[cy1 * WW + cx0]; v11 = xb[cy1 * WW + cx1];
            if (DO_NORM) {
                v00.x = fast_tanh((v00.x - mean0) * g0 + bt0);
                v00.y = fast_tanh((v00.y - mean1) * g1 + bt1);
                v00.z = fast_tanh((v00.z - mean2) * g2 + bt2);
                v01.x = fast_tanh((v01.x - mean0) * g0 + bt0);
                v01.y = fast_tanh((v01.y - mean1) * g1 + bt1);
                v01.z = fast_tanh((v01.z - mean2) * g2 + bt2);
                v10.x = fast_tanh((v10.x - mean0) * g0 + bt0);
                v10.y = fast_tanh((v10.y - mean1) * g1 + bt1);
                v10.z = fast_tanh((v10.z - mean2) * g2 + bt2);
                v11.x = fast_tanh((v11.x - mean0) * g0 + bt0);
                v11.y = fast_tanh((v11.y - mean1) * g1 + bt1);
                v11.z = fast_tanh((v11.z - mean2) * g2 + bt2);
            }
        }

        float s0 = v00.x * w00 + v01.x * w01 + v10.x * w10 + v11.x * w11;
        float s1 = v00.y * w00 + v01.y * w01 + v10.y * w10 + v11.y * w11;
        float s2 = v00.z * w00 + v01.z * w01 + v10.z * w10 + v11.z * w11;
        acc0 = fmaf(s2, w_s[18 + k], fmaf(s1, w_s[ 9 + k], fmaf(s0, w_s[     k], acc0)));
        acc1 = fmaf(s2, w_s[45 + k], fmaf(s1, w_s[36 + k], fmaf(s0, w_s[27 + k], acc1)));
        acc2 = fmaf(s2, w_s[72 + k], fmaf(s1, w_s[63 + k], fmaf(s0, w_s[54 + k], acc2)));
    }

    yo[(size_t)b * HWS + pix] = make_float4(acc0, acc1, acc2, 0.f);

    // ---- per-(b,channel) sum / sumsq reduction (RAW conv output) ----
    float s0r = acc0, q0 = acc0 * acc0;
    float s1r = acc1, q1 = acc1 * acc1;
    float s2r = acc2, q2 = acc2 * acc2;
    #pragma unroll
    for (int o = 32; o > 0; o >>= 1) {
        s0r += __shfl_down(s0r, o); q0 += __shfl_down(q0, o);
        s1r += __shfl_down(s1r, o); q1 += __shfl_down(q1, o);
        s2r += __shfl_down(s2r, o); q2 += __shfl_down(q2, o);
    }
    int wave = t >> 6, lane = t & 63;
    if (lane == 0) {
        red[wave][0] = s0r; red[wave][1] = q0;
        red[wave][2] = s1r; red[wave][3] = q1;
        red[wave][4] = s2r; red[wave][5] = q2;
    }
    __syncthreads();
    if (t < 6) {
        float v = red[0][t] + red[1][t] + red[2][t] + red[3][t];
        int ch = t >> 1, which = t & 1;
        atomicAdd(&stats_out[(b * 3 + ch) * 2 + which], v);
    }
}

// ------------- final instance norm + tanh, scatter to planar output -----------
__global__ __launch_bounds__(256) void norm_final(
    const float4* __restrict__ y, float* __restrict__ outp,
    const float* __restrict__ stats,
    const float* __restrict__ gamma, const float* __restrict__ beta)
{
    int q = blockIdx.x;
    int logical = (q & 7) * ((NPIX/256) / 8) + (q >> 3);
    int b     = logical & 31;
    int chunk = logical >> 5;
    int pix   = chunk * 256 + threadIdx.x;

    float4 v = y[b * HWS + pix];
    float vin[3] = {v.x, v.y, v.z};
    float r[3];
    #pragma unroll
    for (int c = 0; c < 3; ++c) {
        float s  = stats[(b * 3 + c) * 2 + 0];
        float qq = stats[(b * 3 + c) * 2 + 1];
        float mean = s * (1.f / HWS);
        float var  = fmaxf(qq * (1.f / HWS) - mean * mean, 0.f);
        float gsc  = gamma[c] * rsqrtf(var + EPS_IN);
        r[c] = fast_tanh((vin[c] - mean) * gsc + beta[c]);
    }
    float* ob = outp + (size_t)b * (CC * HWS) + pix;
    ob[0]       = r[0];
    ob[HWS]     = r[1];
    ob[2 * HWS] = r[2];
}

extern "C" void kernel_launch(void* const* d_in, const int* in_sizes, int n_in,
                              void* d_out, int out_size, void* d_ws, size_t ws_size,
                              hipStream_t stream) {
    const float* x     = (const float*)d_in[0];
    const float* wt    = (const float*)d_in[1];
    const float* off   = (const float*)d_in[2];   // batch-tiled -> plane 0
    const float* gamma = (const float*)d_in[3];
    const float* beta  = (const float*)d_in[4];

    float* out  = (float*)d_out;
    float*  bufA = (float*)d_ws;                          // NPIX float4 = 25.7 MB
    float*  bufB = bufA + (size_t)NPIX * 4;               // NPIX float4 = 25.7 MB
    float2* tp   = (float2*)(bufB + (size_t)NPIX * 4);    // NTAPS float2 = 3.6 MB
    float*  stats = (float*)((char*)tp + (size_t)NTAPS * 8); // 7.7 KB
    // ws total ~= 55 MB

    zero_kernel<<<(LNUM * 192 + 255) / 256, 256, 0, stream>>>(stats, LNUM * 192);
    taps_kernel<<<NTAPS / 256, 256, 0, stream>>>(off, tp);
    pack_kernel<<<NPIX / 256, 256, 0, stream>>>(x, (float4*)bufB);

    const float4* cur = (const float4*)bufB;   // raw packed x
    const float* st_prev = nullptr;
    for (int it = 0; it < LNUM; ++it) {
        float4* dst = (float4*)((it & 1) ? bufB : bufA);
        float* st = stats + it * 192;
        if (it == 0)
            conv_fused<0><<<NBLK, 256, 0, stream>>>(cur, tp, wt, nullptr,
                                                    gamma, beta, dst, st);
        else
            conv_fused<1><<<NBLK, 256, 0, stream>>>(cur, tp, wt, st_prev,
                                                    gamma, beta, dst, st);
        cur = dst;
        st_prev = st;
    }
    norm_final<<<NPIX / 256, 256, 0, stream>>>(cur, out, st_prev, gamma, beta);
}

// Round 3
// 602.974 us; speedup vs baseline: 6.2027x; 6.2027x over previous
//
#include <hip/hip_runtime.h>
#include <math.h>

#define BB 32
#define CC 3
#define HH 224
#define WW 224
#define HWS (HH*WW)            // 50176
#define NPIX (BB*HWS)          // 1,605,632
#define NTAPS (9*HWS)          // 451,584
#define EPS_IN 1e-5f
#define LNUM 10

// 2D tile: 8 rows x 32 cols per block, halo RAD=7 on each side
#define TR 8
#define TC 32
#define RAD 7
#define WROWS (TR + 2*RAD)         // 22
#define WCOLS (TC + 2*RAD)         // 46 logical
#define WSTRIDE 48                 // padded row stride (float4 cells)
#define WCELLS (WROWS * WCOLS)     // 1012 logical cells staged
#define NTILE ((HH/TR) * (WW/TC))  // 28*7 = 196
#define NBLK (NTILE * BB)          // 6272

__device__ __forceinline__ float fast_tanh(float z) {
    z = fminf(fmaxf(z, -15.f), 15.f);
    float e = __expf(2.f * z);
    return (e - 1.f) * __frcp_rn(e + 1.f);
}

__global__ void zero_kernel(float* __restrict__ p, int n) {
    int i = blockIdx.x * 256 + threadIdx.x;
    if (i < n) p[i] = 0.f;
}

__global__ __launch_bounds__(256) void taps_kernel(
    const float* __restrict__ off, float2* __restrict__ tp)
{
    int gid = blockIdx.x * 256 + threadIdx.x;
    int k = gid / HWS, pix = gid - k * HWS;
    int h = pix / WW, wc = pix - h * WW;
    int ky = k / 3, kx = k - 3 * ky;
    float dy = off[(2 * k)     * HWS + pix];
    float dx = off[(2 * k + 1) * HWS + pix];
    tp[gid] = make_float2((float)(h + ky - 1) + dy, (float)(wc + kx - 1) + dx);
}

__global__ __launch_bounds__(256) void pack_kernel(
    const float* __restrict__ x, float4* __restrict__ xi)
{
    int g = blockIdx.x * 256 + threadIdx.x;
    int b = g / HWS, pix = g - b * HWS;
    const float* xb = x + (size_t)b * (CC * HWS) + pix;
    xi[g] = make_float4(xb[0], xb[HWS], xb[2 * HWS], 0.f);
}

// R3: branch-free hot loop (always-LDS, zero-weighted out-of-window taps),
// single cold fixup loop, one float4 live at a time, launch_bounds(256,2)
// so the allocator never spills (R2's 1.1 GB/dispatch scratch traffic).
template<int DO_NORM>
__global__ __launch_bounds__(256, 2) void conv_fused(
    const float4* __restrict__ xi,
    const float2* __restrict__ tp,
    const float*  __restrict__ wt,
    const float*  __restrict__ stats_in,
    const float*  __restrict__ gamma,
    const float*  __restrict__ beta,
    float4* __restrict__ yo,
    float* __restrict__ stats_out)
{
    __shared__ float4 win[WROWS * WSTRIDE];
    __shared__ float  w_s[81];
    __shared__ float  red[4][6];

    int t = threadIdx.x;
    if (t < 81) w_s[t] = wt[t];

    int p = blockIdx.x;
    int logical = (p & 7) * (NBLK / 8) + (p >> 3);
    int b    = logical & 31;
    int tile = logical >> 5;
    int ty = tile / 7, tx = tile - ty * 7;
    int by0 = ty * TR, bx0 = tx * TC;
    int wly = by0 - RAD, wlx = bx0 - RAD;

    const float4* xb = xi + (size_t)b * HWS;

    int ry = t >> 5, rx = t & 31;
    int pix = (by0 + ry) * WW + (bx0 + rx);

    float2 tpk[9];
    #pragma unroll
    for (int k = 0; k < 9; ++k) tpk[k] = tp[k * HWS + pix];

    float mean0=0.f, mean1=0.f, mean2=0.f;
    float g0=1.f, g1=1.f, g2=1.f, bt0=0.f, bt1=0.f, bt2=0.f;
    if (DO_NORM) {
        const float* st = stats_in + b * 6;
        mean0 = st[0] * (1.f/HWS); mean1 = st[2] * (1.f/HWS); mean2 = st[4] * (1.f/HWS);
        float v0 = fmaxf(st[1]*(1.f/HWS) - mean0*mean0, 0.f);
        float v1 = fmaxf(st[3]*(1.f/HWS) - mean1*mean1, 0.f);
        float v2 = fmaxf(st[5]*(1.f/HWS) - mean2*mean2, 0.f);
        g0 = gamma[0] * rsqrtf(v0 + EPS_IN); bt0 = beta[0];
        g1 = gamma[1] * rsqrtf(v1 + EPS_IN); bt1 = beta[1];
        g2 = gamma[2] * rsqrtf(v2 + EPS_IN); bt2 = beta[2];
    }

    #pragma unroll
    for (int i = 0; i < 4; ++i) {
        int cell = t + i * 256;
        if (cell < WCELLS) {
            int wy = cell / WCOLS, wx = cell - wy * WCOLS;
            int gy = min(max(wly + wy, 0), HH - 1);
            int gx = min(max(wlx + wx, 0), WW - 1);
            float4 v = xb[gy * WW + gx];
            if (DO_NORM) {
                v.x = fast_tanh((v.x - mean0) * g0 + bt0);
                v.y = fast_tanh((v.y - mean1) * g1 + bt1);
                v.z = fast_tanh((v.z - mean2) * g2 + bt2);
            }
            win[wy * WSTRIDE + wx] = v;
        }
    }
    __syncthreads();

    float acc0 = 0.f, acc1 = 0.f, acc2 = 0.f;
    unsigned bad = 0u;

    #pragma unroll
    for (int k = 0; k < 9; ++k) {
        float py = tpk[k].x, px = tpk[k].y;
        float y0f = floorf(py), x0f = floorf(px);
        float fy = py - y0f, fx = px - x0f;
        int iy0 = (int)y0f, ix0 = (int)x0f;
        int iy1 = iy0 + 1,  ix1 = ix0 + 1;
        float vy0 = (iy0 >= 0 && iy0 < HH) ? 1.f : 0.f;
        float vy1 = (iy1 >= 0 && iy1 < HH) ? 1.f : 0.f;
        float vx0 = (ix0 >= 0 && ix0 < WW) ? 1.f : 0.f;
        float vx1 = (ix1 >= 0 && ix1 < WW) ? 1.f : 0.f;
        bool inw = (iy0 >= wly) & (iy0 <= wly + WROWS - 2) &
                   (ix0 >= wlx) & (ix0 <= wlx + WCOLS - 2);
        float m = inw ? 1.f : 0.f;
        bad |= (inw ? 0u : 1u) << k;
        float w00 = (1.f - fy) * (1.f - fx) * vy0 * vx0 * m;
        float w01 = (1.f - fy) * fx         * vy0 * vx1 * m;
        float w10 = fy         * (1.f - fx) * vy1 * vx0 * m;
        float w11 = fy         * fx         * vy1 * vx1 * m;

        int cy = min(max(iy0 - wly, 0), WROWS - 2);
        int cx = min(max(ix0 - wlx, 0), WCOLS - 2);
        int base = cy * WSTRIDE + cx;

        float4 v = win[base];
        float s0 = v.x * w00, s1 = v.y * w00, s2 = v.z * w00;
        v = win[base + 1];
        s0 = fmaf(v.x, w01, s0); s1 = fmaf(v.y, w01, s1); s2 = fmaf(v.z, w01, s2);
        v = win[base + WSTRIDE];
        s0 = fmaf(v.x, w10, s0); s1 = fmaf(v.y, w10, s1); s2 = fmaf(v.z, w10, s2);
        v = win[base + WSTRIDE + 1];
        s0 = fmaf(v.x, w11, s0); s1 = fmaf(v.y, w11, s1); s2 = fmaf(v.z, w11, s2);

        acc0 = fmaf(s2, w_s[18 + k], fmaf(s1, w_s[ 9 + k], fmaf(s0, w_s[     k], acc0)));
        acc1 = fmaf(s2, w_s[45 + k], fmaf(s1, w_s[36 + k], fmaf(s0, w_s[27 + k], acc1)));
        acc2 = fmaf(s2, w_s[72 + k], fmaf(s1, w_s[63 + k], fmaf(s0, w_s[54 + k], acc2)));
    }

    if (__builtin_expect(bad != 0u, 0)) {
        float fm0=0.f, fm1=0.f, fm2=0.f, fg0=1.f, fg1=1.f, fg2=1.f;
        float fb0=0.f, fb1=0.f, fb2=0.f;
        if (DO_NORM) {
            const float* st = stats_in + b * 6;
            fm0 = st[0] * (1.f/HWS); fm1 = st[2] * (1.f/HWS); fm2 = st[4] * (1.f/HWS);
            float v0 = fmaxf(st[1]*(1.f/HWS) - fm0*fm0, 0.f);
            float v1 = fmaxf(st[3]*(1.f/HWS) - fm1*fm1, 0.f);
            float v2 = fmaxf(st[5]*(1.f/HWS) - fm2*fm2, 0.f);
            fg0 = gamma[0] * rsqrtf(v0 + EPS_IN); fb0 = beta[0];
            fg1 = gamma[1] * rsqrtf(v1 + EPS_IN); fb1 = beta[1];
            fg2 = gamma[2] * rsqrtf(v2 + EPS_IN); fb2 = beta[2];
        }
        while (bad) {
            int k = __ffs(bad) - 1; bad &= bad - 1;
            float2 tpv = tp[k * HWS + pix];
            float py = tpv.x, px = tpv.y;
            float y0f = floorf(py), x0f = floorf(px);
            float fy = py - y0f, fx = px - x0f;
            int iy0 = (int)y0f, ix0 = (int)x0f;
            int iy1 = iy0 + 1,  ix1 = ix0 + 1;
            float vy0 = (iy0 >= 0 && iy0 < HH) ? 1.f : 0.f;
            float vy1 = (iy1 >= 0 && iy1 < HH) ? 1.f : 0.f;
            float vx0 = (ix0 >= 0 && ix0 < WW) ? 1.f : 0.f;
            float vx1 = (ix1 >= 0 && ix1 < WW) ? 1.f : 0.f;
            float w00 = (1.f - fy) * (1.f - fx) * vy0 * vx0;
            float w01 = (1.f - fy) * fx         * vy0 * vx1;
            float w10 = fy         * (1.f - fx) * vy1 * vx0;
            float w11 = fy         * fx         * vy1 * vx1;
            int cy0 = min(max(iy0, 0), HH - 1), cy1 = min(max(iy1, 0), HH - 1);
            int cx0 = min(max(ix0, 0), WW - 1), cx1 = min(max(ix1, 0), WW - 1);
            float s0, s1, s2;
            float4 v = xb[cy0 * WW + cx0];
            if (DO_NORM) { v.x = fast_tanh((v.x-fm0)*fg0+fb0); v.y = fast_tanh((v.y-fm1)*fg1+fb1); v.z = fast_tanh((v.z-fm2)*fg2+fb2); }
            s0 = v.x * w00; s1 = v.y * w00; s2 = v.z * w00;
            v = xb[cy0 * WW + cx1];
            if (DO_NORM) { v.x = fast_tanh((v.x-fm0)*fg0+fb0); v.y = fast_tanh((v.y-fm1)*fg1+fb1); v.z = fast_tanh((v.z-fm2)*fg2+fb2); }
            s0 = fmaf(v.x, w01, s0); s1 = fmaf(v.y, w01, s1); s2 = fmaf(v.z, w01, s2);
            v = xb[cy1 * WW + cx0];
            if (DO_NORM) { v.x = fast_tanh((v.x-fm0)*fg0+fb0); v.y = fast_tanh((v.y-fm1)*fg1+fb1); v.z = fast_tanh((v.z-fm2)*fg2+fb2); }
            s0 = fmaf(v.x, w10, s0); s1 = fmaf(v.y, w10, s1); s2 = fmaf(v.z, w10, s2);
            v = xb[cy1 * WW + cx1];
            if (DO_NORM) { v.x = fast_tanh((v.x-fm0)*fg0+fb0); v.y = fast_tanh((v.y-fm1)*fg1+fb1); v.z = fast_tanh((v.z-fm2)*fg2+fb2); }
            s0 = fmaf(v.x, w11, s0); s1 = fmaf(v.y, w11, s1); s2 = fmaf(v.z, w11, s2);
            acc0 = fmaf(s2, w_s[18 + k], fmaf(s1, w_s[ 9 + k], fmaf(s0, w_s[     k], acc0)));
            acc1 = fmaf(s2, w_s[45 + k], fmaf(s1, w_s[36 + k], fmaf(s0, w_s[27 + k], acc1)));
            acc2 = fmaf(s2, w_s[72 + k], fmaf(s1, w_s[63 + k], fmaf(s0, w_s[54 + k], acc2)));
        }
    }

    yo[(size_t)b * HWS + pix] = make_float4(acc0, acc1, acc2, 0.f);

    float s0r = acc0, q0 = acc0 * acc0;
    float s1r = acc1, q1 = acc1 * acc1;
    float s2r = acc2, q2 = acc2 * acc2;
    #pragma unroll
    for (int o = 32; o > 0; o >>= 1) {
        s0r += __shfl_down(s0r, o); q0 += __shfl_down(q0, o);
        s1r += __shfl_down(s1r, o); q1 += __shfl_down(q1, o);
        s2r += __shfl_down(s2r, o); q2 += __shfl_down(q2, o);
    }
    int wave = t >> 6, lane = t & 63;
    if (lane == 0) {
        red[wave][0] = s0r; red[wave][1] = q0;
        red[wave][2] = s1r; red[wave][3] = q1;
        red[wave][4] = s2r; red[wave][5] = q2;
    }
    __syncthreads();
    if (t < 6) {
        float v = red[0][t] + red[1][t] + red[2][t] + red[3][t];
        int ch = t >> 1, which = t & 1;
        atomicAdd(&stats_out[(b * 3 + ch) * 2 + which], v);
    }
}

__global__ __launch_bounds__(256) void norm_final(
    const float4* __restrict__ y, float* __restrict__ outp,
    const float* __restrict__ stats,
    const float* __restrict__ gamma, const float* __restrict__ beta)
{
    int q = blockIdx.x;
    int logical = (q & 7) * ((NPIX/256) / 8) + (q >> 3);
    int b     = logical & 31;
    int chunk = logical >> 5;
    int pix   = chunk * 256 + threadIdx.x;

    float4 v = y[b * HWS + pix];
    float vin[3] = {v.x, v.y, v.z};
    float r[3];
    #pragma unroll
    for (int c = 0; c < 3; ++c) {
        float s  = stats[(b * 3 + c) * 2 + 0];
        float qq = stats[(b * 3 + c) * 2 + 1];
        float mean = s * (1.f / HWS);
        float var  = fmaxf(qq * (1.f / HWS) - mean * mean, 0.f);
        float gsc  = gamma[c] * rsqrtf(var + EPS_IN);
        r[c] = fast_tanh((vin[c] - mean) * gsc + beta[c]);
    }
    float* ob = outp + (size_t)b * (CC * HWS) + pix;
    ob[0]       = r[0];
    ob[HWS]     = r[1];
    ob[2 * HWS] = r[2];
}

extern "C" void kernel_launch(void* const* d_in, const int* in_sizes, int n_in,
                              void* d_out, int out_size, void* d_ws, size_t ws_size,
                              hipStream_t stream) {
    const float* x     = (const float*)d_in[0];
    const float* wt    = (const float*)d_in[1];
    const float* off   = (const float*)d_in[2];
    const float* gamma = (const float*)d_in[3];
    const float* beta  = (const float*)d_in[4];

    float* out  = (float*)d_out;
    float*  bufA = (float*)d_ws;
    float*  bufB = bufA + (size_t)NPIX * 4;
    float2* tp   = (float2*)(bufB + (size_t)NPIX * 4);
    float*  stats = (float*)((char*)tp + (size_t)NTAPS * 8);

    zero_kernel<<<(LNUM * 192 + 255) / 256, 256, 0, stream>>>(stats, LNUM * 192);
    taps_kernel<<<NTAPS / 256, 256, 0, stream>>>(off, tp);
    pack_kernel<<<NPIX / 256, 256, 0, stream>>>(x, (float4*)bufB);

    const float4* cur = (const float4*)bufB;
    const float* st_prev = nullptr;
    for (int it = 0; it < LNUM; ++it) {
        float4* dst = (float4*)((it & 1) ? bufB : bufA);
        float* st = stats + it * 192;
        if (it == 0)
            conv_fused<0><<<NBLK, 256, 0, stream>>>(cur, tp, wt, nullptr,
                                                    gamma, beta, dst, st);
        else
            conv_fused<1><<<NBLK, 256, 0, stream>>>(cur, tp, wt, st_prev,
                                                    gamma, beta, dst, st);
        cur = dst;
        st_prev = st;
    }
    norm_final<<<NPIX / 256, 256, 0, stream>>>(cur, out, st_prev, gamma, beta);
}

// Round 4
// 546.918 us; speedup vs baseline: 6.8384x; 1.1025x over previous
//
#include <hip/hip_runtime.h>
#include <math.h>

#define BB 32
#define CC 3
#define HH 224
#define WW 224
#define HWS (HH*WW)            // 50176
#define NPIX (BB*HWS)          // 1,605,632
#define NTAPS (9*HWS)          // 451,584
#define EPS_IN 1e-5f
#define LNUM 10

// 2D tile: 8 rows x 32 cols per block, halo RAD=4 on each side.
// RAD=4 covers |offset| <= 3 (P ~ 2e-9 per tap to exceed); the cold fixup
// loop handles anything larger, so correctness never depends on RAD.
#define TR 8
#define TC 32
#define RAD 4
#define WROWS (TR + 2*RAD)         // 16
#define WCOLS (TC + 2*RAD)         // 40
#define WSTRIDE 40                 // row stride (float4 cells)
#define WCELLS (WROWS * WCOLS)     // 640
#define NTILE ((HH/TR) * (WW/TC))  // 28*7 = 196
#define NBLK (NTILE * BB)          // 6272

__device__ __forceinline__ float fast_tanh(float z) {
    z = fminf(fmaxf(z, -15.f), 15.f);
    float e = __expf(2.f * z);
    return (e - 1.f) * __frcp_rn(e + 1.f);
}

__global__ void zero_kernel(float* __restrict__ p, int n) {
    int i = blockIdx.x * 256 + threadIdx.x;
    if (i < n) p[i] = 0.f;
}

// ------- precompute per-tap: border-masked bilinear weights (float4) and
// corner coords packed as 2 x short (int). Layer-invariant work hoisted out
// of the 10x conv loop (R3 post-mortem: conv was VALU-issue-bound on exactly
// this expansion). Weight math is bit-identical to the old in-conv version.
__global__ __launch_bounds__(256) void taps_kernel(
    const float* __restrict__ off,   // [18,H,W] batch-0 offset plane
    float4* __restrict__ tw,         // [9,HW] weights (border-masked)
    int*    __restrict__ tc)         // [9,HW] packed (ix0<<16)|(iy0&0xffff)
{
    int gid = blockIdx.x * 256 + threadIdx.x;    // k*HWS + pix, grid exact
    int k = gid / HWS, pix = gid - k * HWS;
    int h = pix / WW, wc = pix - h * WW;
    int ky = k / 3, kx = k - 3 * ky;
    float dy = off[(2 * k)     * HWS + pix];
    float dx = off[(2 * k + 1) * HWS + pix];
    float py = (float)(h  + ky - 1) + dy;
    float px = (float)(wc + kx - 1) + dx;
    float y0f = floorf(py), x0f = floorf(px);
    float fy = py - y0f, fx = px - x0f;
    int iy0 = (int)y0f, ix0 = (int)x0f;
    int iy1 = iy0 + 1,  ix1 = ix0 + 1;
    float vy0 = (iy0 >= 0 && iy0 < HH) ? 1.f : 0.f;
    float vy1 = (iy1 >= 0 && iy1 < HH) ? 1.f : 0.f;
    float vx0 = (ix0 >= 0 && ix0 < WW) ? 1.f : 0.f;
    float vx1 = (ix1 >= 0 && ix1 < WW) ? 1.f : 0.f;
    float4 w;
    w.x = (1.f - fy) * (1.f - fx) * vy0 * vx0;
    w.y = (1.f - fy) * fx         * vy0 * vx1;
    w.z = fy         * (1.f - fx) * vy1 * vx0;
    w.w = fy         * fx         * vy1 * vx1;
    tw[gid] = w;
    // clamp for short packing; anything that far out has all-zero weights
    int cy = min(max(iy0, -30000), 30000);
    int cx = min(max(ix0, -30000), 30000);
    tc[gid] = (cx << 16) | (cy & 0xffff);
}

__global__ __launch_bounds__(256) void pack_kernel(
    const float* __restrict__ x, float4* __restrict__ xi)
{
    int g = blockIdx.x * 256 + threadIdx.x;
    int b = g / HWS, pix = g - b * HWS;
    const float* xb = x + (size_t)b * (CC * HWS) + pix;
    xi[g] = make_float4(xb[0], xb[HWS], xb[2 * HWS], 0.f);
}

// R4: precomputed weights/coords; hot loop = unpack + window-test + 4 LDS
// reads + 21 essential FMAs per tap. launch_bounds(256,3): VGPR cap ~160
// (no spill risk for this slim loop), 12 waves/CU for latency overlap.
template<int DO_NORM>
__global__ __launch_bounds__(256, 3) void conv_fused(
    const float4* __restrict__ xi,       // prev RAW activations [B*HWS]
    const float4* __restrict__ tw,       // [9,HW] masked bilinear weights
    const int*    __restrict__ tc,       // [9,HW] packed corner coords
    const float*  __restrict__ wt,       // [3,3,9]
    const float*  __restrict__ stats_in, // [B*3][2] prev layer
    const float*  __restrict__ gamma,
    const float*  __restrict__ beta,
    float4* __restrict__ yo,             // RAW conv out [B*HWS]
    float* __restrict__ stats_out)       // [B*3][2] this layer
{
    __shared__ float4 win[WROWS * WSTRIDE];
    __shared__ float  w_s[81];
    __shared__ float  red[4][6];

    int t = threadIdx.x;
    if (t < 81) w_s[t] = wt[t];

    int p = blockIdx.x;
    int logical = (p & 7) * (NBLK / 8) + (p >> 3);
    int b    = logical & 31;
    int tile = logical >> 5;
    int ty = tile / 7, tx = tile - ty * 7;
    int by0 = ty * TR, bx0 = tx * TC;
    int wly = by0 - RAD, wlx = bx0 - RAD;

    const float4* xb = xi + (size_t)b * HWS;

    int ry = t >> 5, rx = t & 31;
    int pix = (by0 + ry) * WW + (bx0 + rx);

    // hoist packed corner coords (9 VGPRs, independent load stream)
    int tck[9];
    #pragma unroll
    for (int k = 0; k < 9; ++k) tck[k] = tc[k * HWS + pix];

    // uniform per-(b,c) norm params of the PREVIOUS layer (staging only)
    float mean0=0.f, mean1=0.f, mean2=0.f;
    float g0=1.f, g1=1.f, g2=1.f, bt0=0.f, bt1=0.f, bt2=0.f;
    if (DO_NORM) {
        const float* st = stats_in + b * 6;
        mean0 = st[0] * (1.f/HWS); mean1 = st[2] * (1.f/HWS); mean2 = st[4] * (1.f/HWS);
        float v0 = fmaxf(st[1]*(1.f/HWS) - mean0*mean0, 0.f);
        float v1 = fmaxf(st[3]*(1.f/HWS) - mean1*mean1, 0.f);
        float v2 = fmaxf(st[5]*(1.f/HWS) - mean2*mean2, 0.f);
        g0 = gamma[0] * rsqrtf(v0 + EPS_IN); bt0 = beta[0];
        g1 = gamma[1] * rsqrtf(v1 + EPS_IN); bt1 = beta[1];
        g2 = gamma[2] * rsqrtf(v2 + EPS_IN); bt2 = beta[2];
    }

    // ---- stage window (norm+tanh of prev layer applied on the fly) ----
    #pragma unroll
    for (int i = 0; i < 3; ++i) {
        int cell = t + i * 256;
        if (cell < WCELLS) {
            int wy = cell / WCOLS, wx = cell - wy * WCOLS;
            int gy = min(max(wly + wy, 0), HH - 1);   // clamp: value only used
            int gx = min(max(wlx + wx, 0), WW - 1);   // when weight != 0
            float4 v = xb[gy * WW + gx];
            if (DO_NORM) {
                v.x = fast_tanh((v.x - mean0) * g0 + bt0);
                v.y = fast_tanh((v.y - mean1) * g1 + bt1);
                v.z = fast_tanh((v.z - mean2) * g2 + bt2);
            }
            win[wy * WSTRIDE + wx] = v;
        }
    }
    __syncthreads();

    float acc0 = 0.f, acc1 = 0.f, acc2 = 0.f;
    unsigned bad = 0u;

    #pragma unroll
    for (int k = 0; k < 9; ++k) {
        int pc  = tck[k];
        int iy0 = (int)(short)(pc & 0xffff);
        int ix0 = pc >> 16;
        int cy = iy0 - wly, cx = ix0 - wlx;
        bool inw = ((unsigned)cy <= (unsigned)(WROWS - 2)) &
                   ((unsigned)cx <= (unsigned)(WCOLS - 2));
        float m = inw ? 1.f : 0.f;
        bad |= (inw ? 0u : 1u) << k;

        float4 w = tw[k * HWS + pix];
        w.x *= m; w.y *= m; w.z *= m; w.w *= m;

        int cyc = min(max(cy, 0), WROWS - 2);
        int cxc = min(max(cx, 0), WCOLS - 2);
        int base = cyc * WSTRIDE + cxc;

        float4 v = win[base];
        float s0 = v.x * w.x, s1 = v.y * w.x, s2 = v.z * w.x;
        v = win[base + 1];
        s0 = fmaf(v.x, w.y, s0); s1 = fmaf(v.y, w.y, s1); s2 = fmaf(v.z, w.y, s2);
        v = win[base + WSTRIDE];
        s0 = fmaf(v.x, w.z, s0); s1 = fmaf(v.y, w.z, s1); s2 = fmaf(v.z, w.z, s2);
        v = win[base + WSTRIDE + 1];
        s0 = fmaf(v.x, w.w, s0); s1 = fmaf(v.y, w.w, s1); s2 = fmaf(v.z, w.w, s2);

        acc0 = fmaf(s2, w_s[18 + k], fmaf(s1, w_s[ 9 + k], fmaf(s0, w_s[     k], acc0)));
        acc1 = fmaf(s2, w_s[45 + k], fmaf(s1, w_s[36 + k], fmaf(s0, w_s[27 + k], acc1)));
        acc2 = fmaf(s2, w_s[72 + k], fmaf(s1, w_s[63 + k], fmaf(s0, w_s[54 + k], acc2)));
    }

    // ---- COLD fixup: taps outside the halo (|offset| > 3), essentially never ----
    if (__builtin_expect(bad != 0u, 0)) {
        float fm0=0.f, fm1=0.f, fm2=0.f, fg0=1.f, fg1=1.f, fg2=1.f;
        float fb0=0.f, fb1=0.f, fb2=0.f;
        if (DO_NORM) {
            const float* st = stats_in + b * 6;
            fm0 = st[0] * (1.f/HWS); fm1 = st[2] * (1.f/HWS); fm2 = st[4] * (1.f/HWS);
            float v0 = fmaxf(st[1]*(1.f/HWS) - fm0*fm0, 0.f);
            float v1 = fmaxf(st[3]*(1.f/HWS) - fm1*fm1, 0.f);
            float v2 = fmaxf(st[5]*(1.f/HWS) - fm2*fm2, 0.f);
            fg0 = gamma[0] * rsqrtf(v0 + EPS_IN); fb0 = beta[0];
            fg1 = gamma[1] * rsqrtf(v1 + EPS_IN); fb1 = beta[1];
            fg2 = gamma[2] * rsqrtf(v2 + EPS_IN); fb2 = beta[2];
        }
        while (bad) {
            int k = __ffs(bad) - 1; bad &= bad - 1;
            int pc  = tc[k * HWS + pix];
            int iy0 = (int)(short)(pc & 0xffff);
            int ix0 = pc >> 16;
            float4 w = tw[k * HWS + pix];   // already border-masked
            int cy0 = min(max(iy0, 0), HH - 1), cy1 = min(max(iy0 + 1, 0), HH - 1);
            int cx0 = min(max(ix0, 0), WW - 1), cx1 = min(max(ix0 + 1, 0), WW - 1);
            float s0, s1, s2;
            float4 v = xb[cy0 * WW + cx0];
            if (DO_NORM) { v.x = fast_tanh((v.x-fm0)*fg0+fb0); v.y = fast_tanh((v.y-fm1)*fg1+fb1); v.z = fast_tanh((v.z-fm2)*fg2+fb2); }
            s0 = v.x * w.x; s1 = v.y * w.x; s2 = v.z * w.x;
            v = xb[cy0 * WW + cx1];
            if (DO_NORM) { v.x = fast_tanh((v.x-fm0)*fg0+fb0); v.y = fast_tanh((v.y-fm1)*fg1+fb1); v.z = fast_tanh((v.z-fm2)*fg2+fb2); }
            s0 = fmaf(v.x, w.y, s0); s1 = fmaf(v.y, w.y, s1); s2 = fmaf(v.z, w.y, s2);
            v = xb[cy1 * WW + cx0];
            if (DO_NORM) { v.x = fast_tanh((v.x-fm0)*fg0+fb0); v.y = fast_tanh((v.y-fm1)*fg1+fb1); v.z = fast_tanh((v.z-fm2)*fg2+fb2); }
            s0 = fmaf(v.x, w.z, s0); s1 = fmaf(v.y, w.z, s1); s2 = fmaf(v.z, w.z, s2);
            v = xb[cy1 * WW + cx1];
            if (DO_NORM) { v.x = fast_tanh((v.x-fm0)*fg0+fb0); v.y = fast_tanh((v.y-fm1)*fg1+fb1); v.z = fast_tanh((v.z-fm2)*fg2+fb2); }
            s0 = fmaf(v.x, w.w, s0); s1 = fmaf(v.y, w.w, s1); s2 = fmaf(v.z, w.w, s2);
            acc0 = fmaf(s2, w_s[18 + k], fmaf(s1, w_s[ 9 + k], fmaf(s0, w_s[     k], acc0)));
            acc1 = fmaf(s2, w_s[45 + k], fmaf(s1, w_s[36 + k], fmaf(s0, w_s[27 + k], acc1)));
            acc2 = fmaf(s2, w_s[72 + k], fmaf(s1, w_s[63 + k], fmaf(s0, w_s[54 + k], acc2)));
        }
    }

    yo[(size_t)b * HWS + pix] = make_float4(acc0, acc1, acc2, 0.f);

    // ---- per-(b,channel) sum / sumsq reduction (RAW conv output) ----
    float s0r = acc0, q0 = acc0 * acc0;
    float s1r = acc1, q1 = acc1 * acc1;
    float s2r = acc2, q2 = acc2 * acc2;
    #pragma unroll
    for (int o = 32; o > 0; o >>= 1) {
        s0r += __shfl_down(s0r, o); q0 += __shfl_down(q0, o);
        s1r += __shfl_down(s1r, o); q1 += __shfl_down(q1, o);
        s2r += __shfl_down(s2r, o); q2 += __shfl_down(q2, o);
    }
    int wave = t >> 6, lane = t & 63;
    if (lane == 0) {
        red[wave][0] = s0r; red[wave][1] = q0;
        red[wave][2] = s1r; red[wave][3] = q1;
        red[wave][4] = s2r; red[wave][5] = q2;
    }
    __syncthreads();
    if (t < 6) {
        float v = red[0][t] + red[1][t] + red[2][t] + red[3][t];
        int ch = t >> 1, which = t & 1;
        atomicAdd(&stats_out[(b * 3 + ch) * 2 + which], v);
    }
}

__global__ __launch_bounds__(256) void norm_final(
    const float4* __restrict__ y, float* __restrict__ outp,
    const float* __restrict__ stats,
    const float* __restrict__ gamma, const float* __restrict__ beta)
{
    int q = blockIdx.x;
    int logical = (q & 7) * ((NPIX/256) / 8) + (q >> 3);
    int b     = logical & 31;
    int chunk = logical >> 5;
    int pix   = chunk * 256 + threadIdx.x;

    float4 v = y[b * HWS + pix];
    float vin[3] = {v.x, v.y, v.z};
    float r[3];
    #pragma unroll
    for (int c = 0; c < 3; ++c) {
        float s  = stats[(b * 3 + c) * 2 + 0];
        float qq = stats[(b * 3 + c) * 2 + 1];
        float mean = s * (1.f / HWS);
        float var  = fmaxf(qq * (1.f / HWS) - mean * mean, 0.f);
        float gsc  = gamma[c] * rsqrtf(var + EPS_IN);
        r[c] = fast_tanh((vin[c] - mean) * gsc + beta[c]);
    }
    float* ob = outp + (size_t)b * (CC * HWS) + pix;
    ob[0]       = r[0];
    ob[HWS]     = r[1];
    ob[2 * HWS] = r[2];
}

extern "C" void kernel_launch(void* const* d_in, const int* in_sizes, int n_in,
                              void* d_out, int out_size, void* d_ws, size_t ws_size,
                              hipStream_t stream) {
    const float* x     = (const float*)d_in[0];
    const float* wt    = (const float*)d_in[1];
    const float* off   = (const float*)d_in[2];
    const float* gamma = (const float*)d_in[3];
    const float* beta  = (const float*)d_in[4];

    float* out  = (float*)d_out;
    float*  bufA = (float*)d_ws;                             // 25.7 MB
    float*  bufB = bufA + (size_t)NPIX * 4;                  // 25.7 MB
    float4* tw   = (float4*)(bufB + (size_t)NPIX * 4);       // 7.2 MB
    int*    tc   = (int*)((char*)tw + (size_t)NTAPS * 16);   // 1.8 MB
    float*  stats = (float*)((char*)tc + (size_t)NTAPS * 4); // 7.7 KB
    // ws total ~= 60.5 MB

    zero_kernel<<<(LNUM * 192 + 255) / 256, 256, 0, stream>>>(stats, LNUM * 192);
    taps_kernel<<<NTAPS / 256, 256, 0, stream>>>(off, tw, tc);
    pack_kernel<<<NPIX / 256, 256, 0, stream>>>(x, (float4*)bufB);

    const float4* cur = (const float4*)bufB;
    const float* st_prev = nullptr;
    for (int it = 0; it < LNUM; ++it) {
        float4* dst = (float4*)((it & 1) ? bufB : bufA);
        float* st = stats + it * 192;
        if (it == 0)
            conv_fused<0><<<NBLK, 256, 0, stream>>>(cur, tw, tc, wt, nullptr,
                                                    gamma, beta, dst, st);
        else
            conv_fused<1><<<NBLK, 256, 0, stream>>>(cur, tw, tc, wt, st_prev,
                                                    gamma, beta, dst, st);
        cur = dst;
        st_prev = st;
    }
    norm_final<<<NPIX / 256, 256, 0, stream>>>(cur, out, st_prev, gamma, beta);
}